// Round 2
// baseline (234.247 us; speedup 1.0000x reference)
//
#include <hip/hip_runtime.h>
#include <hip/hip_bf16.h>
#include <math.h>

#define B 8
#define C 512
#define L 2048

using bf16x8 = __bf16 __attribute__((ext_vector_type(8)));
using f32x4  = float __attribute__((ext_vector_type(4)));

#define MFMA(a, b, c) __builtin_amdgcn_mfma_f32_16x16x32_bf16((a), (b), (c), 0, 0, 0)
// exp(v*SCALE - 12) == exp2(v*SC2 + SH2), SCALE = 1/sqrt(512)
#define SC2 0.06375872f
#define SH2 -17.312340f
// compile-time-only memory fence: pins compiler-visible memory ops in-phase
#define MEMFENCE() asm volatile("" ::: "memory")
#define BAR()  do { MEMFENCE(); __builtin_amdgcn_s_barrier(); MEMFENCE(); } while (0)
// rule #18: lgkmcnt wait must be followed by sched_barrier(0) or MFMA hoists past
#define LGKM0() do { asm volatile("s_waitcnt lgkmcnt(0)" ::: "memory"); \
                     __builtin_amdgcn_sched_barrier(0); } while (0)

// RNE f32->bf16 without NaN handling (all values here are finite)
__device__ __forceinline__ unsigned short f2bf(float f) {
    unsigned int u; __builtin_memcpy(&u, &f, 4);
    u += 0x7FFF + ((u >> 16) & 1);
    return (unsigned short)(u >> 16);
}
// async global->LDS, 16B/lane; LDS dest = wave-uniform base + lane*16
__device__ __forceinline__ void load_lds16(const unsigned short* g, unsigned short* l) {
    __builtin_amdgcn_global_load_lds(
        (const __attribute__((address_space(1))) unsigned int*)g,
        (__attribute__((address_space(3))) unsigned int*)l, 16, 0, 0);
}
// inline-asm ds_read_b128: invisible to SIInsertWaitcnts' LDS-DMA alias
// tracking, so staging loads stay in flight (we do our own lgkm/vmcnt waits)
__device__ __forceinline__ bf16x8 dsr128(unsigned byteoff) {
    bf16x8 r;
    asm volatile("ds_read_b128 %0, %1" : "=v"(r) : "v"(byteoff));
    return r;
}

// ---------------------------------------------------------------------------
// GEMM-NT core (legacy 128x128, 2-barrier): used by qkv_gemm / pv_gemm.
// MODE 0: +bias[col], bf16 out      (QKV q/k)
// MODE 1: +bias[row], bf16 out      (QKV v)
// MODE 3: /ep[col], f32 out         (PV, ep = row sums)
// ---------------------------------------------------------------------------
template<int MODE, int KDIM>
__device__ __forceinline__ void gemm_core(
    const unsigned short* __restrict__ A,   // pre-offset to tile row m0
    const unsigned short* __restrict__ Bm,  // pre-offset to tile row n0
    unsigned short* As, unsigned short* Bs, // [2][128*32] each
    void* __restrict__ OutV, int ldo,       // pre-offset to (m0, n0)
    float* __restrict__ ep)                 // bias / rsum (pre-offset)
{
    const int t = threadIdx.x;
    const int wave = t >> 6, lane = t & 63;
    const int ll = t & 15, quad = (t >> 4) & 3;
    const int lr = lane >> 2, chunk = lane & 3;
    const int wm = (wave & 1) * 64, wn = (wave >> 1) * 64;

    const unsigned short* gA0 = A  + (size_t)(wave * 32 + lr) * KDIM + chunk * 8;
    const unsigned short* gB0 = Bm + (size_t)(wave * 32 + lr) * KDIM + chunk * 8;
    unsigned short* lA0 = As + (wave * 32) * 32;        // wave-uniform bases
    unsigned short* lB0 = Bs + (wave * 32) * 32;
    const int P1 = 128 * 32;                            // panel-1 offset

    f32x4 acc[4][4];
#pragma unroll
    for (int i = 0; i < 4; ++i)
#pragma unroll
        for (int j = 0; j < 4; ++j) acc[i][j] = (f32x4){0.f, 0.f, 0.f, 0.f};

#pragma unroll 1
    for (int k0 = 0; k0 < KDIM; k0 += 64) {
        __syncthreads();                      // prev compute done reading LDS
        load_lds16(gA0 + k0, lA0);
        load_lds16(gA0 + (size_t)16 * KDIM + k0, lA0 + 16 * 32);
        load_lds16(gA0 + k0 + 32, lA0 + P1);
        load_lds16(gA0 + (size_t)16 * KDIM + k0 + 32, lA0 + P1 + 16 * 32);
        load_lds16(gB0 + k0, lB0);
        load_lds16(gB0 + (size_t)16 * KDIM + k0, lB0 + 16 * 32);
        load_lds16(gB0 + k0 + 32, lB0 + P1);
        load_lds16(gB0 + (size_t)16 * KDIM + k0 + 32, lB0 + P1 + 16 * 32);
        __syncthreads();                      // staging visible

#pragma unroll
        for (int p = 0; p < 2; ++p) {
            bf16x8 af[4], bf[4];
#pragma unroll
            for (int mi = 0; mi < 4; ++mi)
                af[mi] = *(const bf16x8*)&As[p * P1 + (wm + mi * 16 + ll) * 32 + quad * 8];
#pragma unroll
            for (int ni = 0; ni < 4; ++ni)
                bf[ni] = *(const bf16x8*)&Bs[p * P1 + (wn + ni * 16 + ll) * 32 + quad * 8];
#pragma unroll
            for (int mi = 0; mi < 4; ++mi)
#pragma unroll
                for (int ni = 0; ni < 4; ++ni)
                    acc[mi][ni] = MFMA(af[mi], bf[ni], acc[mi][ni]);
        }
    }

#pragma unroll
    for (int mi = 0; mi < 4; ++mi)
#pragma unroll
        for (int ni = 0; ni < 4; ++ni) {
            const int col = wn + ni * 16 + ll;
            float epc = 0.f;
            if (MODE == 0) epc = ep[col];
            if (MODE == 3) epc = 1.0f / ep[col];
#pragma unroll
            for (int r = 0; r < 4; ++r) {
                const int row = wm + mi * 16 + quad * 4 + r;
                float v = acc[mi][ni][r];
                if (MODE == 0)      v += epc;
                else if (MODE == 1) v += ep[row];
                else                v *= epc;
                if (MODE == 3)
                    ((float*)OutV)[(size_t)row * ldo + col] = v;
                else
                    ((unsigned short*)OutV)[(size_t)row * ldo + col] = f2bf(v);
            }
        }
}

// ---------------------------------------------------------------------------
// Kernel 0a: x [B][C][L] fp32 -> xt [B][L][C] bf16 (64x64 tile, vectorized)
// ---------------------------------------------------------------------------
__global__ __launch_bounds__(256) void xpose_cvt(
    const float* __restrict__ x, unsigned short* __restrict__ xt)
{
    __shared__ float tile[64][69];
    const int b = blockIdx.z, l0 = blockIdx.x * 64, c0 = blockIdx.y * 64;
    const int t = threadIdx.x;
    const int lx = t & 15, cy = t >> 4;          // load: float4 along L
    const float* xb = x + (size_t)b * C * L;
#pragma unroll
    for (int p = 0; p < 4; ++p) {
        float4 v = *(const float4*)(xb + (size_t)(c0 + p * 16 + cy) * L + l0 + lx * 4);
        tile[p * 16 + cy][lx * 4 + 0] = v.x;
        tile[p * 16 + cy][lx * 4 + 1] = v.y;
        tile[p * 16 + cy][lx * 4 + 2] = v.z;
        tile[p * 16 + cy][lx * 4 + 3] = v.w;
    }
    __syncthreads();
    const int ocl = t & 15, ot = t >> 4;         // store: 4 bf16 (8B) along C
    unsigned short* xtb = xt + (size_t)b * L * C;
#pragma unroll
    for (int p = 0; p < 4; ++p) {
        int ol = p * 16 + ot;
        union { unsigned short h[4]; uint2 u; } pk;
#pragma unroll
        for (int i = 0; i < 4; ++i) pk.h[i] = f2bf(tile[ocl * 4 + i][ol]);
        *(uint2*)(xtb + (size_t)(l0 + ol) * C + c0 + ocl * 4) = pk.u;
    }
}

// ---------------------------------------------------------------------------
// Kernel 0b: Wq|Wk|Wv fp32 -> contiguous bf16; blocks 0..15 also zero rsum
// ---------------------------------------------------------------------------
__global__ __launch_bounds__(256) void wcvt(
    const float* __restrict__ Wq, const float* __restrict__ Wk,
    const float* __restrict__ Wv, unsigned short* __restrict__ o,
    float* __restrict__ rsum)
{
    if (blockIdx.x < 16) {   // zero rsum[B*L] = 16384 floats
        float4 z = make_float4(0.f, 0.f, 0.f, 0.f);
        *(float4*)(rsum + (blockIdx.x * 256 + threadIdx.x) * 4) = z;
    }
    const int i = (blockIdx.x * 256 + threadIdx.x) * 4;
    const int which = i >> 18;                            // C*C = 2^18
    const int off = i & 0x3FFFF;
    const float* src = (which == 0) ? Wq : (which == 1) ? Wk : Wv;
    float4 v = *(const float4*)(src + off);
    union { unsigned short h[4]; uint2 u; } pk;
    pk.h[0] = f2bf(v.x); pk.h[1] = f2bf(v.y); pk.h[2] = f2bf(v.z); pk.h[3] = f2bf(v.w);
    *(uint2*)(o + i) = pk.u;
}

// ---------------------------------------------------------------------------
// Kernel 1: QKV projection. 1-D grid 1536: b = id&7 (XCD), r = id>>3:
//   which = r>>6; q/k: m = tt&15 (fastest), n = tt>>4; v: m = tt&3, n = tt>>2
// ---------------------------------------------------------------------------
__global__ __launch_bounds__(256) void qkv_gemm(
    const unsigned short* __restrict__ xt, const unsigned short* __restrict__ Wb,
    const float* __restrict__ bq, const float* __restrict__ bk,
    const float* __restrict__ bv,
    unsigned short* __restrict__ Qt, unsigned short* __restrict__ Kt,
    unsigned short* __restrict__ Vv)
{
    __shared__ unsigned short As[2 * 128 * 32], Bs[2 * 128 * 32];
    const int id = blockIdx.x;
    const int b = id & 7, r = id >> 3;          // r in 0..191
    const int which = r >> 6, tt = r & 63;
    const unsigned short* xtb = xt + (size_t)b * L * C;
    if (which < 2) {
        const int m0 = (tt & 15) * 128, n0 = (tt >> 4) * 128;   // M=L, N=C
        const unsigned short* A  = xtb + (size_t)m0 * C;
        const unsigned short* Bm = Wb + (size_t)which * C * C + (size_t)n0 * C;
        unsigned short* Out = (which ? Kt : Qt) + (size_t)b * L * C
                              + (size_t)m0 * C + n0;
        gemm_core<0, C>(A, Bm, As, Bs, Out, C,
                        const_cast<float*>((which ? bk : bq) + n0));
    } else {
        const int m0 = (tt & 3) * 128, n0 = (tt >> 2) * 128;    // M=C, N=L
        const unsigned short* A  = Wb + (size_t)2 * C * C + (size_t)m0 * C;
        const unsigned short* Bm = xtb + (size_t)n0 * C;
        unsigned short* Out = Vv + (size_t)b * C * L + (size_t)m0 * L + n0;
        gemm_core<1, C>(A, Bm, As, Bs, Out, L, const_cast<float*>(bv + m0));
    }
}

// ---------------------------------------------------------------------------
// Kernel 2: P = exp(Q K^T * scale - 12) + fused row-sum atomics.
// 256x256 tile, 512 thr = 8 waves (2M x 4N, per-wave 128x64), BK=64,
// 4 phases/K-tile, double-buffered 128 KiB LDS, XOR-swizzled reads with
// pre-swizzled global source (global_load_lds writes linearly), counted
// vmcnt(4) once per K-tile (never 0 in the loop), setprio around MFMA.
// Fragment reads are inline-asm ds_read_b128 (dsr128) so the compiler's
// waitcnt pass cannot insert per-phase vmcnt drains against the LDS-DMA
// staging writes (it can't disambiguate As[kt&1] vs As[(kt+1)&1]); all
// LDS-read ordering is via explicit lgkmcnt(0)+sched_barrier after each
// leading barrier.
//
// Stage schedule (per K-tile kt; uniform order across waves):
//   ph0: A(kt+1) h0   -> As[(kt+1)&1]   (slot of A(kt-1), reads retired)
//   ph1: A(kt+1) h1
//   ph2: B(kt+2) h0   -> Bs[kt&1]       (B(kt) read entirely in ph0)
//   ph3: B(kt+2) h1, then vmcnt(4): retires A(kt+1)+B(kt+1) for ALL waves
//        (uniform issue order), leaves exactly B(kt+2)'s 4 loads in flight.
// Tail iterations stage clamped (dummy) tiles so counts stay uniform; the
// dummy data lands in slots that are never read again.
// ---------------------------------------------------------------------------
__global__ __launch_bounds__(512, 2) void sc_exp2(
    const unsigned short* __restrict__ Qt, const unsigned short* __restrict__ Kt,
    unsigned short* __restrict__ P, float* __restrict__ rsum,
    int hoff, int qrows, int mshift)
{
    __shared__ unsigned short As[2][16384], Bs[2][16384];   // 128 KiB total
    constexpr int KD = C;          // K dimension
    constexpr int NT = C / 64;     // 8 K-tiles

    const int id = blockIdx.x;
    const int b = id & 7, rr = id >> 3;
    const int m0 = (rr & ((1 << mshift) - 1)) * 256, n0 = (rr >> mshift) * 256;
    const unsigned short* A  = Qt + (size_t)b * L * C + (size_t)(hoff + m0) * C;
    const unsigned short* Bm = Kt + (size_t)b * L * C + (size_t)n0 * C;
    unsigned short* Out = P + (size_t)b * qrows * L + (size_t)m0 * L + n0;
    float* ep = rsum + (size_t)b * L + hoff + m0;

    const int t = threadIdx.x;
    const int wave = t >> 6, lane = t & 63;
    const int ll = lane & 15, quad = lane >> 4;
    const int wm = wave & 1, wn = wave >> 1;       // 2M x 4N waves
    // ---- staging source pre-swizzle: LDS(row, c16) holds global chunk
    //      c16 ^ (row&7); writer lane t covers row r0=t>>3 (+64*j),
    //      LDS chunk t&7 -> fetch global chunk (t&7)^(r0&7).
    const int r0 = t >> 3;
    const int swz = ((t & 7) ^ (r0 & 7)) * 8;      // elements
    // ---- swizzled read chunk byte-offsets (row&7 == ll&7 for all frag rows)
    const int sw8 = ll & 7;
    const unsigned c0b = (unsigned)(((quad ^ sw8)) * 16);        // kk=0
    const unsigned c1b = (unsigned)((((4 + quad) ^ sw8)) * 16);  // kk=1
    const unsigned aBb = (unsigned)(wm * 16384 + ll * 128);      // A row base (bytes)
    const unsigned bBb = (unsigned)(wn * 8192  + ll * 128);      // B row base (bytes)
    const unsigned ldsA = (unsigned)(unsigned long long)&As[0][0];
    const unsigned ldsB = (unsigned)(unsigned long long)&Bs[0][0];

    const unsigned short* gA = A  + (size_t)r0 * KD + swz;
    const unsigned short* gB = Bm + (size_t)r0 * KD + swz;

    f32x4 acc[8][4];
#pragma unroll
    for (int i = 0; i < 8; ++i)
#pragma unroll
        for (int j = 0; j < 4; ++j) acc[i][j] = (f32x4){0.f, 0.f, 0.f, 0.f};

    // -------- prologue: A(0) [4 loads], B(0) [4], B(1) [4]; keep B(1) in flight
    {
        unsigned short* sA0 = &As[0][0] + wave * 512;
        unsigned short* sB0 = &Bs[0][0] + wave * 512;
        unsigned short* sB1 = &Bs[1][0] + wave * 512;
        load_lds16(gA,                          sA0);            // A(0) h0 j0
        load_lds16(gA + (size_t)64  * KD,       sA0 + 4096);     // A(0) h0 j1
        load_lds16(gA + (size_t)128 * KD,       sA0 + 8192);     // A(0) h1 j0
        load_lds16(gA + (size_t)192 * KD,       sA0 + 12288);    // A(0) h1 j1
        load_lds16(gB,                          sB0);            // B(0)
        load_lds16(gB + (size_t)64  * KD,       sB0 + 4096);
        load_lds16(gB + (size_t)128 * KD,       sB0 + 8192);
        load_lds16(gB + (size_t)192 * KD,       sB0 + 12288);
        load_lds16(gB + 64,                     sB1);            // B(1)
        load_lds16(gB + (size_t)64  * KD + 64,  sB1 + 4096);
        load_lds16(gB + (size_t)128 * KD + 64,  sB1 + 8192);
        load_lds16(gB + (size_t)192 * KD + 64,  sB1 + 12288);
        asm volatile("s_waitcnt vmcnt(4)" ::: "memory");  // A(0),B(0) landed
        __builtin_amdgcn_sched_barrier(0);
        BAR();
    }

#define CLUSTER(base)                                                          \
    __builtin_amdgcn_s_setprio(1);                                             \
    _Pragma("unroll")                                                          \
    for (int mi2 = 0; mi2 < 2; ++mi2)                                          \
        _Pragma("unroll")                                                      \
        for (int ni = 0; ni < 4; ++ni) {                                       \
            acc[(base) + mi2][ni] = MFMA(af[mi2][0], bfr[ni][0], acc[(base) + mi2][ni]); \
            acc[(base) + mi2][ni] = MFMA(af[mi2][1], bfr[ni][1], acc[(base) + mi2][ni]); \
        }                                                                      \
    __builtin_amdgcn_s_setprio(0);

#pragma unroll 1
    for (int kt = 0; kt < NT; ++kt) {
        const int p = kt & 1;
        const unsigned aAdr = ldsA + (unsigned)(p * 32768) + aBb;
        const unsigned bAdr = ldsB + (unsigned)(p * 32768) + bBb;
        const int kaOff = (kt + 1 < NT ? kt + 1 : 0) * 64;   // clamp = dummy
        const int kbOff = (kt + 2 < NT ? kt + 2 : 0) * 64;
        unsigned short* stA = &As[(kt + 1) & 1][0] + wave * 512;
        unsigned short* stB = &Bs[p][0] + wave * 512;        // (kt+2)&1 == p

        bf16x8 bfr[4][2], af[2][2];

        // ======== phase 0: all B-frags + A-quad0; stage A(kt+1) h0 ========
#pragma unroll
        for (int ni = 0; ni < 4; ++ni) {
            bfr[ni][0] = dsr128(bAdr + ni * 2048 + c0b);
            bfr[ni][1] = dsr128(bAdr + ni * 2048 + c1b);
        }
        af[0][0] = dsr128(aAdr + 0 * 2048 + c0b);
        af[0][1] = dsr128(aAdr + 0 * 2048 + c1b);
        af[1][0] = dsr128(aAdr + 1 * 2048 + c0b);
        af[1][1] = dsr128(aAdr + 1 * 2048 + c1b);
        load_lds16(gA + kaOff,                    stA);
        load_lds16(gA + (size_t)64 * KD + kaOff,  stA + 4096);
        BAR();
        LGKM0();
        CLUSTER(0);
        BAR();

        // ======== phase 1: A-quad1; stage A(kt+1) h1 ========
        af[0][0] = dsr128(aAdr + 2 * 2048 + c0b);
        af[0][1] = dsr128(aAdr + 2 * 2048 + c1b);
        af[1][0] = dsr128(aAdr + 3 * 2048 + c0b);
        af[1][1] = dsr128(aAdr + 3 * 2048 + c1b);
        load_lds16(gA + (size_t)128 * KD + kaOff, stA + 8192);
        load_lds16(gA + (size_t)192 * KD + kaOff, stA + 12288);
        BAR();
        LGKM0();
        CLUSTER(2);
        BAR();

        // ======== phase 2: A-quad2; stage B(kt+2) h0 ========
        af[0][0] = dsr128(aAdr + 4 * 2048 + c0b);
        af[0][1] = dsr128(aAdr + 4 * 2048 + c1b);
        af[1][0] = dsr128(aAdr + 5 * 2048 + c0b);
        af[1][1] = dsr128(aAdr + 5 * 2048 + c1b);
        load_lds16(gB + kbOff,                    stB);
        load_lds16(gB + (size_t)64 * KD + kbOff,  stB + 4096);
        BAR();
        LGKM0();
        CLUSTER(4);
        BAR();

        // ======== phase 3: A-quad3; stage B(kt+2) h1; vmcnt(4) ========
        af[0][0] = dsr128(aAdr + 6 * 2048 + c0b);
        af[0][1] = dsr128(aAdr + 6 * 2048 + c1b);
        af[1][0] = dsr128(aAdr + 7 * 2048 + c0b);
        af[1][1] = dsr128(aAdr + 7 * 2048 + c1b);
        load_lds16(gB + (size_t)128 * KD + kbOff, stB + 8192);
        load_lds16(gB + (size_t)192 * KD + kbOff, stB + 12288);
        BAR();
        LGKM0();
        CLUSTER(6);
        asm volatile("s_waitcnt vmcnt(4)" ::: "memory");  // A(kt+1),B(kt+1) in
        __builtin_amdgcn_sched_barrier(0);
        BAR();
    }
#undef CLUSTER

    // -------- epilogue: exp2, bf16 store, fused row sums (no LDS use;
    //          up to 4 dummy staging loads may still be in flight -> harmless)
    float rpart[8][4];
#pragma unroll
    for (int mi = 0; mi < 8; ++mi)
#pragma unroll
        for (int r = 0; r < 4; ++r) rpart[mi][r] = 0.f;

#pragma unroll
    for (int mi = 0; mi < 8; ++mi)
#pragma unroll
        for (int ni = 0; ni < 4; ++ni) {
            const int col = wn * 64 + ni * 16 + ll;
#pragma unroll
            for (int r = 0; r < 4; ++r) {
                const int row = wm * 128 + mi * 16 + quad * 4 + r;
                float v = exp2f(fmaf(acc[mi][ni][r], SC2, SH2));
                rpart[mi][r] += v;
                Out[(size_t)row * L + col] = f2bf(v);
            }
        }
#pragma unroll
    for (int mi = 0; mi < 8; ++mi)
#pragma unroll
        for (int r = 0; r < 4; ++r) {
            float s = rpart[mi][r];
            s += __shfl_xor(s, 1, 64);
            s += __shfl_xor(s, 2, 64);
            s += __shfl_xor(s, 4, 64);
            s += __shfl_xor(s, 8, 64);
            if (ll == 0) atomicAdd(ep + wm * 128 + mi * 16 + quad * 4 + r, s);
        }
}

// ---------------------------------------------------------------------------
// Kernel 3: O = (V @ P^T) / rsum[col]
// 1-D grid: b = id&7 (XCD), r = id>>3, m = r&3 fastest (M=C: 4 tiles), n rest
// ---------------------------------------------------------------------------
__global__ __launch_bounds__(256) void pv_gemm(
    const unsigned short* __restrict__ Vv, const unsigned short* __restrict__ P,
    const float* __restrict__ rsum, float* __restrict__ out,
    int hoff, int qrows)
{
    __shared__ unsigned short As[2 * 128 * 32], Bs[2 * 128 * 32];
    const int id = blockIdx.x;
    const int b = id & 7, r = id >> 3;
    const int m0 = (r & 3) * 128, n0 = (r >> 2) * 128;
    const unsigned short* A  = Vv + (size_t)b * C * L + (size_t)m0 * L;
    const unsigned short* Bm = P + (size_t)b * qrows * L + (size_t)n0 * L;
    float* Out = out + (size_t)b * C * L + (size_t)m0 * L + hoff + n0;
    float* ep = const_cast<float*>(rsum) + (size_t)b * L + hoff + n0;
    gemm_core<3, L>(A, Bm, As, Bs, Out, L, ep);
}

extern "C" void kernel_launch(void* const* d_in, const int* in_sizes, int n_in,
                              void* d_out, int out_size, void* d_ws, size_t ws_size,
                              hipStream_t stream) {
    const float* x  = (const float*)d_in[0];
    const float* Wq = (const float*)d_in[1];
    const float* bq = (const float*)d_in[2];
    const float* Wk = (const float*)d_in[3];
    const float* bk = (const float*)d_in[4];
    const float* Wv = (const float*)d_in[5];
    const float* bv = (const float*)d_in[6];
    float* out = (float*)d_out;

    const size_t BCL = (size_t)B * C * L;                // 8.39M elems
    const bool fullP = ws_size >= 119078912ull;          // full-P footprint

    unsigned short* Qt = (unsigned short*)d_ws;          // [B][L][C] bf16
    unsigned short* Kt = Qt + BCL;
    unsigned short* Vv = Kt + BCL;                       // [B][C][L]
    unsigned short *Wb, *xt, *P;
    float* rsum;
    if (fullP) {
        Wb   = Vv + BCL;                                 // 1.57 MB, live during qkv
        rsum = (float*)(Wb + (size_t)3 * C * C);         // [B][L] f32
        xt   = (unsigned short*)(rsum + (size_t)B * L);  // dead after qkv
        P    = xt;                                       // [B][L][L] bf16, aliases xt
    } else {                                             // 85.6 MB fallback
        xt   = Vv + BCL;
        P    = xt;                                       // [B][1024][L], aliases xt
        Wb   = P + (size_t)B * 1024 * L;
        rsum = (float*)(Wb + (size_t)3 * C * C);
    }

    xpose_cvt<<<dim3(L / 64, C / 64, B), 256, 0, stream>>>(x, xt);
    wcvt<<<dim3(3 * C * C / 1024), 256, 0, stream>>>(Wq, Wk, Wv, Wb, rsum);
    qkv_gemm<<<dim3(1536), 256, 0, stream>>>(xt, Wb, bq, bk, bv, Qt, Kt, Vv);

    if (fullP) {
        sc_exp2<<<dim3(512), 512, 0, stream>>>(Qt, Kt, P, rsum, 0, L, 3);
        pv_gemm<<<dim3(512), 256, 0, stream>>>(Vv, P, rsum, out, 0, L);
    } else {
        for (int h = 0; h < 2; ++h) {
            sc_exp2<<<dim3(256), 512, 0, stream>>>(Qt, Kt, P, rsum, h * 1024, 1024, 2);
            pv_gemm<<<dim3(256), 256, 0, stream>>>(Vv, P, rsum, out, h * 1024, 1024);
        }
    }
}

// Round 3
// 231.561 us; speedup vs baseline: 1.0116x; 1.0116x over previous
//
#include <hip/hip_runtime.h>
#include <hip/hip_bf16.h>
#include <math.h>

#define B 8
#define C 512
#define L 2048

using bf16x8 = __bf16 __attribute__((ext_vector_type(8)));
using f32x4  = float __attribute__((ext_vector_type(4)));

#define MFMA(a, b, c) __builtin_amdgcn_mfma_f32_16x16x32_bf16((a), (b), (c), 0, 0, 0)
// exp(v*SCALE - 12) == exp2(v*SC2 + SH2), SCALE = 1/sqrt(512)
#define SC2 0.06375872f
#define SH2 -17.312340f
// compile-time-only memory fence: pins compiler-visible memory ops in-phase
#define MEMFENCE() asm volatile("" ::: "memory")
#define BAR()  do { MEMFENCE(); __builtin_amdgcn_s_barrier(); MEMFENCE(); } while (0)
// rule #18: lgkm wait must be followed by sched_barrier(0) or MFMA hoists past.
// Counted variant: ds ops retire in order per wave, so lgkmcnt(N) waits for all
// but the N most-recently-issued ds_reads (global_load_lds does NOT touch lgkm).
#define LGKMC(n) do { asm volatile("s_waitcnt lgkmcnt(" #n ")" ::: "memory"); \
                      __builtin_amdgcn_sched_barrier(0); } while (0)

// RNE f32->bf16 without NaN handling (all values here are finite)
__device__ __forceinline__ unsigned short f2bf(float f) {
    unsigned int u; __builtin_memcpy(&u, &f, 4);
    u += 0x7FFF + ((u >> 16) & 1);
    return (unsigned short)(u >> 16);
}
// async global->LDS, 16B/lane; LDS dest = wave-uniform base + lane*16
__device__ __forceinline__ void load_lds16(const unsigned short* g, unsigned short* l) {
    __builtin_amdgcn_global_load_lds(
        (const __attribute__((address_space(1))) unsigned int*)g,
        (__attribute__((address_space(3))) unsigned int*)l, 16, 0, 0);
}
// inline-asm ds_read_b128: invisible to SIInsertWaitcnts (no compiler-inserted
// drains against LDS-DMA); all ordering via explicit counted lgkm/vmcnt waits.
__device__ __forceinline__ bf16x8 dsr128(unsigned byteoff) {
    bf16x8 r;
    asm volatile("ds_read_b128 %0, %1" : "=v"(r) : "v"(byteoff));
    return r;
}

// ---------------------------------------------------------------------------
// GEMM-NT core (legacy 128x128, 2-barrier): used by qkv_gemm / pv_gemm.
// MODE 0: +bias[col], bf16 out      (QKV q/k)
// MODE 1: +bias[row], bf16 out      (QKV v)
// MODE 3: /ep[col], f32 out         (PV, ep = row sums)
// ---------------------------------------------------------------------------
template<int MODE, int KDIM>
__device__ __forceinline__ void gemm_core(
    const unsigned short* __restrict__ A,   // pre-offset to tile row m0
    const unsigned short* __restrict__ Bm,  // pre-offset to tile row n0
    unsigned short* As, unsigned short* Bs, // [2][128*32] each
    void* __restrict__ OutV, int ldo,       // pre-offset to (m0, n0)
    float* __restrict__ ep)                 // bias / rsum (pre-offset)
{
    const int t = threadIdx.x;
    const int wave = t >> 6, lane = t & 63;
    const int ll = t & 15, quad = (t >> 4) & 3;
    const int lr = lane >> 2, chunk = lane & 3;
    const int wm = (wave & 1) * 64, wn = (wave >> 1) * 64;

    const unsigned short* gA0 = A  + (size_t)(wave * 32 + lr) * KDIM + chunk * 8;
    const unsigned short* gB0 = Bm + (size_t)(wave * 32 + lr) * KDIM + chunk * 8;
    unsigned short* lA0 = As + (wave * 32) * 32;        // wave-uniform bases
    unsigned short* lB0 = Bs + (wave * 32) * 32;
    const int P1 = 128 * 32;                            // panel-1 offset

    f32x4 acc[4][4];
#pragma unroll
    for (int i = 0; i < 4; ++i)
#pragma unroll
        for (int j = 0; j < 4; ++j) acc[i][j] = (f32x4){0.f, 0.f, 0.f, 0.f};

#pragma unroll 1
    for (int k0 = 0; k0 < KDIM; k0 += 64) {
        __syncthreads();                      // prev compute done reading LDS
        load_lds16(gA0 + k0, lA0);
        load_lds16(gA0 + (size_t)16 * KDIM + k0, lA0 + 16 * 32);
        load_lds16(gA0 + k0 + 32, lA0 + P1);
        load_lds16(gA0 + (size_t)16 * KDIM + k0 + 32, lA0 + P1 + 16 * 32);
        load_lds16(gB0 + k0, lB0);
        load_lds16(gB0 + (size_t)16 * KDIM + k0, lB0 + 16 * 32);
        load_lds16(gB0 + k0 + 32, lB0 + P1);
        load_lds16(gB0 + (size_t)16 * KDIM + k0 + 32, lB0 + P1 + 16 * 32);
        __syncthreads();                      // staging visible

#pragma unroll
        for (int p = 0; p < 2; ++p) {
            bf16x8 af[4], bf[4];
#pragma unroll
            for (int mi = 0; mi < 4; ++mi)
                af[mi] = *(const bf16x8*)&As[p * P1 + (wm + mi * 16 + ll) * 32 + quad * 8];
#pragma unroll
            for (int ni = 0; ni < 4; ++ni)
                bf[ni] = *(const bf16x8*)&Bs[p * P1 + (wn + ni * 16 + ll) * 32 + quad * 8];
#pragma unroll
            for (int mi = 0; mi < 4; ++mi)
#pragma unroll
                for (int ni = 0; ni < 4; ++ni)
                    acc[mi][ni] = MFMA(af[mi], bf[ni], acc[mi][ni]);
        }
    }

#pragma unroll
    for (int mi = 0; mi < 4; ++mi)
#pragma unroll
        for (int ni = 0; ni < 4; ++ni) {
            const int col = wn + ni * 16 + ll;
            float epc = 0.f;
            if (MODE == 0) epc = ep[col];
            if (MODE == 3) epc = 1.0f / ep[col];
#pragma unroll
            for (int r = 0; r < 4; ++r) {
                const int row = wm + mi * 16 + quad * 4 + r;
                float v = acc[mi][ni][r];
                if (MODE == 0)      v += epc;
                else if (MODE == 1) v += ep[row];
                else                v *= epc;
                if (MODE == 3)
                    ((float*)OutV)[(size_t)row * ldo + col] = v;
                else
                    ((unsigned short*)OutV)[(size_t)row * ldo + col] = f2bf(v);
            }
        }
}

// ---------------------------------------------------------------------------
// Kernel 0a: x [B][C][L] fp32 -> xt [B][L][C] bf16 (64x64 tile, vectorized)
// ---------------------------------------------------------------------------
__global__ __launch_bounds__(256) void xpose_cvt(
    const float* __restrict__ x, unsigned short* __restrict__ xt)
{
    __shared__ float tile[64][69];
    const int b = blockIdx.z, l0 = blockIdx.x * 64, c0 = blockIdx.y * 64;
    const int t = threadIdx.x;
    const int lx = t & 15, cy = t >> 4;          // load: float4 along L
    const float* xb = x + (size_t)b * C * L;
#pragma unroll
    for (int p = 0; p < 4; ++p) {
        float4 v = *(const float4*)(xb + (size_t)(c0 + p * 16 + cy) * L + l0 + lx * 4);
        tile[p * 16 + cy][lx * 4 + 0] = v.x;
        tile[p * 16 + cy][lx * 4 + 1] = v.y;
        tile[p * 16 + cy][lx * 4 + 2] = v.z;
        tile[p * 16 + cy][lx * 4 + 3] = v.w;
    }
    __syncthreads();
    const int ocl = t & 15, ot = t >> 4;         // store: 4 bf16 (8B) along C
    unsigned short* xtb = xt + (size_t)b * L * C;
#pragma unroll
    for (int p = 0; p < 4; ++p) {
        int ol = p * 16 + ot;
        union { unsigned short h[4]; uint2 u; } pk;
#pragma unroll
        for (int i = 0; i < 4; ++i) pk.h[i] = f2bf(tile[ocl * 4 + i][ol]);
        *(uint2*)(xtb + (size_t)(l0 + ol) * C + c0 + ocl * 4) = pk.u;
    }
}

// ---------------------------------------------------------------------------
// Kernel 0b: Wq|Wk|Wv fp32 -> contiguous bf16; blocks 0..15 also zero rsum
// ---------------------------------------------------------------------------
__global__ __launch_bounds__(256) void wcvt(
    const float* __restrict__ Wq, const float* __restrict__ Wk,
    const float* __restrict__ Wv, unsigned short* __restrict__ o,
    float* __restrict__ rsum)
{
    if (blockIdx.x < 16) {   // zero rsum[B*L] = 16384 floats
        float4 z = make_float4(0.f, 0.f, 0.f, 0.f);
        *(float4*)(rsum + (blockIdx.x * 256 + threadIdx.x) * 4) = z;
    }
    const int i = (blockIdx.x * 256 + threadIdx.x) * 4;
    const int which = i >> 18;                            // C*C = 2^18
    const int off = i & 0x3FFFF;
    const float* src = (which == 0) ? Wq : (which == 1) ? Wk : Wv;
    float4 v = *(const float4*)(src + off);
    union { unsigned short h[4]; uint2 u; } pk;
    pk.h[0] = f2bf(v.x); pk.h[1] = f2bf(v.y); pk.h[2] = f2bf(v.z); pk.h[3] = f2bf(v.w);
    *(uint2*)(o + i) = pk.u;
}

// ---------------------------------------------------------------------------
// Kernel 1: QKV projection. 1-D grid 1536: b = id&7 (XCD), r = id>>3:
//   which = r>>6; q/k: m = tt&15 (fastest), n = tt>>4; v: m = tt&3, n = tt>>2
// ---------------------------------------------------------------------------
__global__ __launch_bounds__(256) void qkv_gemm(
    const unsigned short* __restrict__ xt, const unsigned short* __restrict__ Wb,
    const float* __restrict__ bq, const float* __restrict__ bk,
    const float* __restrict__ bv,
    unsigned short* __restrict__ Qt, unsigned short* __restrict__ Kt,
    unsigned short* __restrict__ Vv)
{
    __shared__ unsigned short As[2 * 128 * 32], Bs[2 * 128 * 32];
    const int id = blockIdx.x;
    const int b = id & 7, r = id >> 3;          // r in 0..191
    const int which = r >> 6, tt = r & 63;
    const unsigned short* xtb = xt + (size_t)b * L * C;
    if (which < 2) {
        const int m0 = (tt & 15) * 128, n0 = (tt >> 4) * 128;   // M=L, N=C
        const unsigned short* A  = xtb + (size_t)m0 * C;
        const unsigned short* Bm = Wb + (size_t)which * C * C + (size_t)n0 * C;
        unsigned short* Out = (which ? Kt : Qt) + (size_t)b * L * C
                              + (size_t)m0 * C + n0;
        gemm_core<0, C>(A, Bm, As, Bs, Out, C,
                        const_cast<float*>((which ? bk : bq) + n0));
    } else {
        const int m0 = (tt & 3) * 128, n0 = (tt >> 2) * 128;    // M=C, N=L
        const unsigned short* A  = Wb + (size_t)2 * C * C + (size_t)m0 * C;
        const unsigned short* Bm = xtb + (size_t)n0 * C;
        unsigned short* Out = Vv + (size_t)b * C * L + (size_t)m0 * L + n0;
        gemm_core<1, C>(A, Bm, As, Bs, Out, L, const_cast<float*>(bv + m0));
    }
}

// ---------------------------------------------------------------------------
// Kernel 2: P = exp(Q K^T * scale - 12) + fused row-sum atomics.
// 256x256 tile, 512 thr = 8 waves (2M x 4N, per-wave 128x64), BK=64,
// double-buffered 128 KiB LDS, XOR-swizzled reads via pre-swizzled global
// source (global_load_lds writes linearly).
//
// RELAXED-SYNC schedule (this round's change): 2 barriers per K-tile
// (was 8), counted lgkm waits with one-quad-ahead ds_read prefetch, counted
// vmcnt(4) once per K-tile (never 0), setprio around each 16-MFMA cluster.
// Cross-wave hazards needing barriers:
//   BAR mid-tile : stage into Bs[p] (region 2) vs all waves' B-frag reads
//                  (region 1; each wave's reads retired by its first LGKMC).
//   BAR tile-end : stage into As[(kt+1)&1] (next tile) vs reads of same
//                  parity in THIS tile, and vmcnt(4)-certified landing of
//                  A(kt+1)/B(kt+1) made visible to ALL waves.
// Everything else is per-wave: ds ops retire in order -> counted lgkmcnt.
//
// Stage schedule (per K-tile kt; per-wave issue order fixed):
//   region 1: A(kt+1) h0+h1 -> As[(kt+1)&1]
//   region 2: B(kt+2) h0+h1 -> Bs[kt&1], then vmcnt(4): retires
//             B(kt+1)+A(kt+1), leaves exactly B(kt+2)'s 4 loads in flight.
// Invariant: entering tile kt, only B(kt+1)'s 4 loads are outstanding.
// Tails stage clamped (dummy) tiles so counts stay uniform.
// ---------------------------------------------------------------------------
__global__ __launch_bounds__(512, 2) void sc_exp2(
    const unsigned short* __restrict__ Qt, const unsigned short* __restrict__ Kt,
    unsigned short* __restrict__ P, float* __restrict__ rsum,
    int hoff, int qrows, int mshift)
{
    __shared__ unsigned short As[2][16384], Bs[2][16384];   // 128 KiB total
    constexpr int KD = C;          // K dimension
    constexpr int NT = C / 64;     // 8 K-tiles

    const int id = blockIdx.x;
    const int b = id & 7, rr = id >> 3;
    const int m0 = (rr & ((1 << mshift) - 1)) * 256, n0 = (rr >> mshift) * 256;
    const unsigned short* A  = Qt + (size_t)b * L * C + (size_t)(hoff + m0) * C;
    const unsigned short* Bm = Kt + (size_t)b * L * C + (size_t)n0 * C;
    unsigned short* Out = P + (size_t)b * qrows * L + (size_t)m0 * L + n0;
    float* ep = rsum + (size_t)b * L + hoff + m0;

    const int t = threadIdx.x;
    const int wave = t >> 6, lane = t & 63;
    const int ll = lane & 15, quad = lane >> 4;
    const int wm = wave & 1, wn = wave >> 1;       // 2M x 4N waves
    // ---- staging source pre-swizzle: LDS(row, c16) holds global chunk
    //      c16 ^ (row&7); writer lane t covers row r0=t>>3 (+64*j),
    //      LDS chunk t&7 -> fetch global chunk (t&7)^(r0&7).
    const int r0 = t >> 3;
    const int swz = ((t & 7) ^ (r0 & 7)) * 8;      // elements
    // ---- swizzled read chunk byte-offsets (row&7 == ll&7 for all frag rows)
    const int sw8 = ll & 7;
    const unsigned c0b = (unsigned)(((quad ^ sw8)) * 16);        // kk=0
    const unsigned c1b = (unsigned)((((4 + quad) ^ sw8)) * 16);  // kk=1
    const unsigned aBb = (unsigned)(wm * 16384 + ll * 128);      // A row base (bytes)
    const unsigned bBb = (unsigned)(wn * 8192  + ll * 128);      // B row base (bytes)
    const unsigned ldsA = (unsigned)(unsigned long long)&As[0][0];
    const unsigned ldsB = (unsigned)(unsigned long long)&Bs[0][0];

    const unsigned short* gA = A  + (size_t)r0 * KD + swz;
    const unsigned short* gB = Bm + (size_t)r0 * KD + swz;

    f32x4 acc[8][4];
#pragma unroll
    for (int i = 0; i < 8; ++i)
#pragma unroll
        for (int j = 0; j < 4; ++j) acc[i][j] = (f32x4){0.f, 0.f, 0.f, 0.f};

    // -------- prologue: A(0) [4 loads], B(0) [4], B(1) [4]; keep B(1) in flight
    {
        unsigned short* sA0 = &As[0][0] + wave * 512;
        unsigned short* sB0 = &Bs[0][0] + wave * 512;
        unsigned short* sB1 = &Bs[1][0] + wave * 512;
        load_lds16(gA,                          sA0);            // A(0) h0 j0
        load_lds16(gA + (size_t)64  * KD,       sA0 + 4096);     // A(0) h0 j1
        load_lds16(gA + (size_t)128 * KD,       sA0 + 8192);     // A(0) h1 j0
        load_lds16(gA + (size_t)192 * KD,       sA0 + 12288);    // A(0) h1 j1
        load_lds16(gB,                          sB0);            // B(0)
        load_lds16(gB + (size_t)64  * KD,       sB0 + 4096);
        load_lds16(gB + (size_t)128 * KD,       sB0 + 8192);
        load_lds16(gB + (size_t)192 * KD,       sB0 + 12288);
        load_lds16(gB + 64,                     sB1);            // B(1)
        load_lds16(gB + (size_t)64  * KD + 64,  sB1 + 4096);
        load_lds16(gB + (size_t)128 * KD + 64,  sB1 + 8192);
        load_lds16(gB + (size_t)192 * KD + 64,  sB1 + 12288);
        asm volatile("s_waitcnt vmcnt(4)" ::: "memory");  // A(0),B(0) landed
        __builtin_amdgcn_sched_barrier(0);
        BAR();
    }

#define CLUSTER(base, F)                                                       \
    __builtin_amdgcn_s_setprio(1);                                             \
    _Pragma("unroll")                                                          \
    for (int mi2 = 0; mi2 < 2; ++mi2)                                          \
        _Pragma("unroll")                                                      \
        for (int ni = 0; ni < 4; ++ni) {                                       \
            acc[(base) + mi2][ni] = MFMA(F[mi2][0], bfr[ni][0], acc[(base) + mi2][ni]); \
            acc[(base) + mi2][ni] = MFMA(F[mi2][1], bfr[ni][1], acc[(base) + mi2][ni]); \
        }                                                                      \
    __builtin_amdgcn_s_setprio(0);

#pragma unroll 1
    for (int kt = 0; kt < NT; ++kt) {
        const int p = kt & 1;
        const unsigned aAdr = ldsA + (unsigned)(p * 32768) + aBb;
        const unsigned bAdr = ldsB + (unsigned)(p * 32768) + bBb;
        const int kaOff = (kt + 1 < NT ? kt + 1 : 0) * 64;   // clamp = dummy
        const int kbOff = (kt + 2 < NT ? kt + 2 : 0) * 64;
        unsigned short* stA = &As[(kt + 1) & 1][0] + wave * 512;
        unsigned short* stB = &Bs[p][0] + wave * 512;        // (kt+2)&1 == p

        bf16x8 bfr[4][2], afA[2][2], afB[2][2];

        // ================= region 1 (A-quads 0,1; stage A(kt+1)) ===========
        load_lds16(gA + kaOff,                    stA);          // A(kt+1) h0
        load_lds16(gA + (size_t)64 * KD + kaOff,  stA + 4096);
        // 12 ds: all B-frags + A-quad0
#pragma unroll
        for (int ni = 0; ni < 4; ++ni) {
            bfr[ni][0] = dsr128(bAdr + ni * 2048 + c0b);
            bfr[ni][1] = dsr128(bAdr + ni * 2048 + c1b);
        }
        afA[0][0] = dsr128(aAdr + 0 * 2048 + c0b);
        afA[0][1] = dsr128(aAdr + 0 * 2048 + c1b);
        afA[1][0] = dsr128(aAdr + 1 * 2048 + c0b);
        afA[1][1] = dsr128(aAdr + 1 * 2048 + c1b);
        // prefetch A-quad1 (4 ds, allowed to stay outstanding)
        afB[0][0] = dsr128(aAdr + 2 * 2048 + c0b);
        afB[0][1] = dsr128(aAdr + 2 * 2048 + c1b);
        afB[1][0] = dsr128(aAdr + 3 * 2048 + c0b);
        afB[1][1] = dsr128(aAdr + 3 * 2048 + c1b);
        LGKMC(4);                       // B + A-quad0 retired (A-quad1 in flight)
        CLUSTER(0, afA);
        load_lds16(gA + (size_t)128 * KD + kaOff, stA + 8192);   // A(kt+1) h1
        load_lds16(gA + (size_t)192 * KD + kaOff, stA + 12288);
        // prefetch A-quad2
        afA[0][0] = dsr128(aAdr + 4 * 2048 + c0b);
        afA[0][1] = dsr128(aAdr + 4 * 2048 + c1b);
        afA[1][0] = dsr128(aAdr + 5 * 2048 + c0b);
        afA[1][1] = dsr128(aAdr + 5 * 2048 + c1b);
        LGKMC(4);                       // A-quad1 retired (A-quad2 in flight)
        CLUSTER(2, afB);
        BAR();   // B-buffer fence: all waves' B-frag reads retired above

        // ================= region 2 (A-quads 2,3; stage B(kt+2)) ===========
        load_lds16(gB + kbOff,                    stB);          // B(kt+2) h0
        load_lds16(gB + (size_t)64 * KD + kbOff,  stB + 4096);
        // prefetch A-quad3
        afB[0][0] = dsr128(aAdr + 6 * 2048 + c0b);
        afB[0][1] = dsr128(aAdr + 6 * 2048 + c1b);
        afB[1][0] = dsr128(aAdr + 7 * 2048 + c0b);
        afB[1][1] = dsr128(aAdr + 7 * 2048 + c1b);
        LGKMC(4);                       // A-quad2 retired (A-quad3 in flight)
        CLUSTER(4, afA);
        load_lds16(gB + (size_t)128 * KD + kbOff, stB + 8192);   // B(kt+2) h1
        load_lds16(gB + (size_t)192 * KD + kbOff, stB + 12288);
        LGKMC(0);                       // A-quad3 retired
        CLUSTER(6, afB);
        asm volatile("s_waitcnt vmcnt(4)" ::: "memory");  // A(kt+1),B(kt+1) in
        __builtin_amdgcn_sched_barrier(0);
        BAR();   // tile boundary: landing visible to all waves; As reuse fence
    }
#undef CLUSTER

    // -------- epilogue: exp2, bf16 store, fused row sums (no LDS use;
    //          up to 4 dummy staging loads may still be in flight -> harmless)
    float rpart[8][4];
#pragma unroll
    for (int mi = 0; mi < 8; ++mi)
#pragma unroll
        for (int r = 0; r < 4; ++r) rpart[mi][r] = 0.f;

#pragma unroll
    for (int mi = 0; mi < 8; ++mi)
#pragma unroll
        for (int ni = 0; ni < 4; ++ni) {
            const int col = wn * 64 + ni * 16 + ll;
#pragma unroll
            for (int r = 0; r < 4; ++r) {
                const int row = wm * 128 + mi * 16 + quad * 4 + r;
                float v = exp2f(fmaf(acc[mi][ni][r], SC2, SH2));
                rpart[mi][r] += v;
                Out[(size_t)row * L + col] = f2bf(v);
            }
        }
#pragma unroll
    for (int mi = 0; mi < 8; ++mi)
#pragma unroll
        for (int r = 0; r < 4; ++r) {
            float s = rpart[mi][r];
            s += __shfl_xor(s, 1, 64);
            s += __shfl_xor(s, 2, 64);
            s += __shfl_xor(s, 4, 64);
            s += __shfl_xor(s, 8, 64);
            if (ll == 0) atomicAdd(ep + wm * 128 + mi * 16 + quad * 4 + r, s);
        }
}

// ---------------------------------------------------------------------------
// Kernel 3: O = (V @ P^T) / rsum[col]
// 1-D grid: b = id&7 (XCD), r = id>>3, m = r&3 fastest (M=C: 4 tiles), n rest
// ---------------------------------------------------------------------------
__global__ __launch_bounds__(256) void pv_gemm(
    const unsigned short* __restrict__ Vv, const unsigned short* __restrict__ P,
    const float* __restrict__ rsum, float* __restrict__ out,
    int hoff, int qrows)
{
    __shared__ unsigned short As[2 * 128 * 32], Bs[2 * 128 * 32];
    const int id = blockIdx.x;
    const int b = id & 7, r = id >> 3;
    const int m0 = (r & 3) * 128, n0 = (r >> 2) * 128;
    const unsigned short* A  = Vv + (size_t)b * C * L + (size_t)m0 * L;
    const unsigned short* Bm = P + (size_t)b * qrows * L + (size_t)n0 * L;
    float* Out = out + (size_t)b * C * L + (size_t)m0 * L + hoff + n0;
    float* ep = const_cast<float*>(rsum) + (size_t)b * L + hoff + n0;
    gemm_core<3, L>(A, Bm, As, Bs, Out, L, ep);
}

extern "C" void kernel_launch(void* const* d_in, const int* in_sizes, int n_in,
                              void* d_out, int out_size, void* d_ws, size_t ws_size,
                              hipStream_t stream) {
    const float* x  = (const float*)d_in[0];
    const float* Wq = (const float*)d_in[1];
    const float* bq = (const float*)d_in[2];
    const float* Wk = (const float*)d_in[3];
    const float* bk = (const float*)d_in[4];
    const float* Wv = (const float*)d_in[5];
    const float* bv = (const float*)d_in[6];
    float* out = (float*)d_out;

    const size_t BCL = (size_t)B * C * L;                // 8.39M elems
    const bool fullP = ws_size >= 119078912ull;          // full-P footprint

    unsigned short* Qt = (unsigned short*)d_ws;          // [B][L][C] bf16
    unsigned short* Kt = Qt + BCL;
    unsigned short* Vv = Kt + BCL;                       // [B][C][L]
    unsigned short *Wb, *xt, *P;
    float* rsum;
    if (fullP) {
        Wb   = Vv + BCL;                                 // 1.57 MB, live during qkv
        rsum = (float*)(Wb + (size_t)3 * C * C);         // [B][L] f32
        xt   = (unsigned short*)(rsum + (size_t)B * L);  // dead after qkv
        P    = xt;                                       // [B][L][L] bf16, aliases xt
    } else {                                             // 85.6 MB fallback
        xt   = Vv + BCL;
        P    = xt;                                       // [B][1024][L], aliases xt
        Wb   = P + (size_t)B * 1024 * L;
        rsum = (float*)(Wb + (size_t)3 * C * C);
    }

    xpose_cvt<<<dim3(L / 64, C / 64, B), 256, 0, stream>>>(x, xt);
    wcvt<<<dim3(3 * C * C / 1024), 256, 0, stream>>>(Wq, Wk, Wv, Wb, rsum);
    qkv_gemm<<<dim3(1536), 256, 0, stream>>>(xt, Wb, bq, bk, bv, Qt, Kt, Vv);

    if (fullP) {
        sc_exp2<<<dim3(512), 512, 0, stream>>>(Qt, Kt, P, rsum, 0, L, 3);
        pv_gemm<<<dim3(512), 256, 0, stream>>>(Vv, P, rsum, out, 0, L);
    } else {
        for (int h = 0; h < 2; ++h) {
            sc_exp2<<<dim3(256), 512, 0, stream>>>(Qt, Kt, P, rsum, h * 1024, 1024, 2);
            pv_gemm<<<dim3(256), 256, 0, stream>>>(Vv, P, rsum, out, h * 1024, 1024);
        }
    }
}